// Round 5
// baseline (464.753 us; speedup 1.0000x reference)
//
#include <hip/hip_runtime.h>

// Batched Viterbi decode: B=1024, S=512, T=64.  R5: lazy-argmax.
// Forward pass is VALUE-ONLY (add + max3 tree, ~1.5 instr/candidate instead of
// 4) and streams the forward-var history (B*S*T fp32 = 128 MiB) to d_ws.
// Backpointers are recomputed in the fused backtrace ONLY for the tag on the
// path (512 argmaxes/block instead of 512*64): lane p evaluates
// hist[s][p] + trans[tag][p]; 6-stage DPP max-reduce (VALU pipe, ~50cyc) +
// __ballot(c==max) + ctz gives first-index argmax (exact jnp semantics) and a
// wave-uniform next tag. History prefetched 16 steps deep (addresses are
// independent of the serial tag chain). Bit-exact: fp32 max is order-invariant.
// Fallback to the R4 full-argmax kernel if ws_size < 128 MiB.

#define B_ 1024
#define S_ 512
#define T_ 64
#define NEGV -10000.0f

// max over all 64 lanes, result broadcast via lane 63 (gfx9-style DPP ladder)
__device__ __forceinline__ float wave_max64(float v) {
    int x;
#define DPP_MAX(ctrl, rmask)                                                        \
    x = __builtin_amdgcn_update_dpp(__float_as_int(v), __float_as_int(v),           \
                                    ctrl, rmask, 0xf, false);                       \
    v = fmaxf(v, __int_as_float(x));
    DPP_MAX(0x111, 0xf)   // row_shr:1
    DPP_MAX(0x112, 0xf)   // row_shr:2
    DPP_MAX(0x114, 0xf)   // row_shr:4
    DPP_MAX(0x118, 0xf)   // row_shr:8  -> lane15 of each row16 has row max
    DPP_MAX(0x142, 0xa)   // row_bcast:15 -> rows 1,3
    DPP_MAX(0x143, 0xc)   // row_bcast:31 -> rows 2,3 ; lane63 = global max
#undef DPP_MAX
    return __int_as_float(__builtin_amdgcn_readlane(__float_as_int(v), 63));
}

__global__ __launch_bounds__(64, 1) void viterbi_hist_kernel(
    const float* __restrict__ feats,   // [B, S, T]
    const float* __restrict__ trans,   // [T, T]
    float* __restrict__ out,           // [B + B*S]
    float* __restrict__ hist)          // [B, S, T] scratch
{
    __shared__ __align__(16) float fvbuf[2][T_];   // parity-dbuf forward var
    __shared__ __align__(16) float ldsT[T_ * T_];  // transitions, row-major

    const int b = blockIdx.x;
    const int lane = threadIdx.x;      // forward: lane = next tag; backtrace: lane = prev

    // transitions row for next = lane (64 VGPRs)
    float t[T_];
#pragma unroll
    for (int p = 0; p < T_; p += 4) {
        const float4 v = *reinterpret_cast<const float4*>(trans + lane * T_ + p);
        t[p] = v.x; t[p + 1] = v.y; t[p + 2] = v.z; t[p + 3] = v.w;
    }
    const float tend = trans[(T_ - 1) * T_ + lane];   // transitions[END][lane]

    // stage full transitions into LDS for backtrace row reads (one-time).
    // single-wave block: same-wave LDS write->read is in-order, no barrier.
#pragma unroll
    for (int j = 0; j < 16; ++j) {
        float4 v; v.x = t[4*j]; v.y = t[4*j+1]; v.z = t[4*j+2]; v.w = t[4*j+3];
        *reinterpret_cast<float4*>(&ldsT[lane * T_ + 4 * j]) = v;
    }

    float fv = (lane == T_ - 2) ? 0.0f : NEGV;        // START = T-2
    fvbuf[0][lane] = fv;

    const float* fb = feats + (size_t)b * S_ * T_ + lane;
    float* hb = hist + (size_t)b * S_ * T_ + lane;

    // feat prefetch ring: one unrolled body (4 steps) ahead
    float fc[4], fn[4];
#pragma unroll
    for (int k = 0; k < 4; ++k) fc[k] = fb[(size_t)k * T_];

    // ---------------- forward scan (value-only) ----------------
#pragma unroll 1
    for (int s4 = 0; s4 < S_ / 4; ++s4) {
#pragma unroll
        for (int k = 0; k < 4; ++k) {
            int sp = 4 * s4 + 4 + k;
            sp = (sp < S_) ? sp : (S_ - 1);
            fn[k] = fb[(size_t)sp * T_];
        }

#pragma unroll
        for (int u = 0; u < 4; ++u) {
            const int s = 4 * s4 + u;
            const int rs = s & 1;

            hb[(size_t)s * T_] = fv;   // history: forward var ENTERING step s

            // broadcast-read fv vector (16x ds_read_b128, same addr all lanes)
            float fvl[T_];
#pragma unroll
            for (int j = 0; j < 16; ++j) {
                const float4 v = *reinterpret_cast<const float4*>(&fvbuf[rs][4 * j]);
                fvl[4 * j] = v.x; fvl[4 * j + 1] = v.y;
                fvl[4 * j + 2] = v.z; fvl[4 * j + 3] = v.w;
            }

            // candidates + max3 tree (no argmax): 64 adds + ~32 max ops
            float c[T_];
#pragma unroll
            for (int p = 0; p < T_; ++p) c[p] = fvl[p] + t[p];

            float m1[22];
#pragma unroll
            for (int i = 0; i < 21; ++i)
                m1[i] = fmaxf(fmaxf(c[3 * i], c[3 * i + 1]), c[3 * i + 2]);
            m1[21] = c[63];
            float m2[8];
#pragma unroll
            for (int i = 0; i < 7; ++i)
                m2[i] = fmaxf(fmaxf(m1[3 * i], m1[3 * i + 1]), m1[3 * i + 2]);
            m2[7] = m1[21];
            const float m3a = fmaxf(fmaxf(m2[0], m2[1]), m2[2]);
            const float m3b = fmaxf(fmaxf(m2[3], m2[4]), m2[5]);
            const float BV = fmaxf(fmaxf(m3a, m3b), fmaxf(m2[6], m2[7]));

            fv = BV + fc[u];
            fvbuf[rs ^ 1][lane] = fv;
        }
#pragma unroll
        for (int k = 0; k < 4; ++k) fc[k] = fn[k];
    }

    // ---------------- terminal: max + first-index argmax ----------------
    const float tv = fv + tend;
    const float smax = wave_max64(tv);
    const unsigned long long msk = __ballot(tv == smax);
    int tcur = (int)__builtin_ctzll(msk);       // lowest tag on tie = jnp.argmax
    if (lane == 0) out[b] = smax;

    // ---------------- backtrace: lazy per-step argmax ----------------
    float* outp = out + B_ + (size_t)b * S_;

    // history prefetch ring, depth 16; idx = S-1-s walks 0..511
    float hr[16];
#pragma unroll
    for (int d = 0; d < 16; ++d) hr[d] = hb[(size_t)(S_ - 1 - d) * T_];

    int emit = 0;
#pragma unroll 1
    for (int g = 0; g < 32; ++g) {
#pragma unroll
        for (int d = 0; d < 16; ++d) {
            const int idx = 16 * g + d;
            const int s = S_ - 1 - idx;          // 511..0
            const float h = hr[d];
            if (idx + 16 < S_)                   // prefetch step s-16
                hr[d] = hb[(size_t)(s - 16) * T_];

            // candidates for bp[s][tcur]: lane = prev
            const float cnd = h + ldsT[tcur * T_ + lane];
            const float mx = wave_max64(cnd);
            const unsigned long long mk = __ballot(cnd == mx);

            emit = (lane == (s & 63)) ? tcur : emit;   // emit OLD tag at pos s
            tcur = (int)__builtin_ctzll(mk);           // follow backpointer

            if ((s & 63) == 0) {                       // chunk done: store 256B
                outp[s + lane] = (float)emit;
                emit = 0;
            }
        }
    }
}

// ---------------- fallback (ws too small): R4 full-argmax kernel ----------------
__global__ __launch_bounds__(64, 1) void viterbi_fallback_kernel(
    const float* __restrict__ feats, const float* __restrict__ trans,
    float* __restrict__ out)
{
    __shared__ unsigned int bp[S_ / 4][T_];
    __shared__ __align__(16) float fvbuf[2][T_];

    const int b = blockIdx.x;
    const int lane = threadIdx.x;

    float t[T_];
#pragma unroll
    for (int p = 0; p < T_; p += 4) {
        const float4 v = *reinterpret_cast<const float4*>(trans + lane * T_ + p);
        t[p] = v.x; t[p + 1] = v.y; t[p + 2] = v.z; t[p + 3] = v.w;
    }
    const float tend = trans[(T_ - 1) * T_ + lane];

    float fv = (lane == T_ - 2) ? 0.0f : NEGV;
    fvbuf[0][lane] = fv;

    const float* fb = feats + (size_t)b * S_ * T_ + lane;
    unsigned int pack = 0;

#pragma unroll 4
    for (int s = 0; s < S_; ++s) {
        const float feat = fb[(size_t)s * T_];
        const int rs = s & 1;
        float fvl[T_];
#pragma unroll
        for (int j = 0; j < 16; ++j) {
            const float4 v = *reinterpret_cast<const float4*>(&fvbuf[rs][4 * j]);
            fvl[4 * j] = v.x; fvl[4 * j + 1] = v.y;
            fvl[4 * j + 2] = v.z; fvl[4 * j + 3] = v.w;
        }
        float bv[4]; int bi[4];
#pragma unroll
        for (int g = 0; g < 4; ++g) {
            float bestv = fvl[16 * g] + t[16 * g];
            int besti = 16 * g;
#pragma unroll
            for (int q = 1; q < 16; ++q) {
                const int p = 16 * g + q;
                const float c = fvl[p] + t[p];
                const bool gt = c > bestv;
                besti = gt ? p : besti;
                bestv = gt ? c : bestv;
            }
            bv[g] = bestv; bi[g] = besti;
        }
        float BV = bv[0]; int BI = bi[0];
#pragma unroll
        for (int g = 1; g < 4; ++g) {
            const bool gt = bv[g] > BV;
            BI = gt ? bi[g] : BI;
            BV = gt ? bv[g] : BV;
        }
        fv = BV + feat;
        fvbuf[rs ^ 1][lane] = fv;
        pack |= ((unsigned int)BI) << (8 * (s & 3));
        if ((s & 3) == 3) { bp[s >> 2][lane] = pack; pack = 0; }
    }

    float v = fv + tend;
    int i = lane;
#pragma unroll
    for (int off = 1; off < 64; off <<= 1) {
        const float vo = __shfl_xor(v, off);
        const int io = __shfl_xor(i, off);
        const bool take = (vo > v) || ((vo == v) && (io < i));
        v = take ? vo : v;
        i = take ? io : i;
    }
    int tcur = __builtin_amdgcn_readfirstlane(i);
    if (lane == 0) out[b] = v;

    float* outp = out + B_ + (size_t)b * S_;
#pragma unroll 1
    for (int c = 7; c >= 0; --c) {
        unsigned int wd[16];
#pragma unroll
        for (int j = 0; j < 16; ++j) wd[j] = bp[16 * c + j][lane];
        int emit = 0;
#pragma unroll
        for (int k = 63; k >= 0; --k) {
            emit = (lane == k) ? tcur : emit;
            const int word = __builtin_amdgcn_readlane((int)wd[k >> 2], tcur);
            tcur = (word >> (8 * (k & 3))) & 0xff;
        }
        outp[64 * c + lane] = (float)emit;
    }
}

extern "C" void kernel_launch(void* const* d_in, const int* in_sizes, int n_in,
                              void* d_out, int out_size, void* d_ws, size_t ws_size,
                              hipStream_t stream) {
    const float* feats = (const float*)d_in[0];   // [B*S*T] f32
    const float* trans = (const float*)d_in[1];   // [T*T] f32
    float* out = (float*)d_out;                   // [B + B*S] f32
    const size_t need = (size_t)B_ * S_ * T_ * sizeof(float);   // 128 MiB
    if (ws_size >= need) {
        viterbi_hist_kernel<<<dim3(B_), dim3(T_), 0, stream>>>(
            feats, trans, out, (float*)d_ws);
    } else {
        viterbi_fallback_kernel<<<dim3(B_), dim3(T_), 0, stream>>>(feats, trans, out);
    }
}